// Round 8
// baseline (216.523 us; speedup 1.0000x reference)
//
#include <hip/hip_runtime.h>
#include <hip/hip_fp16.h>

typedef _Float16 f16;
typedef f16 f16x8 __attribute__((ext_vector_type(8)));
typedef float f32x4 __attribute__((ext_vector_type(4)));

constexpr int T = 64;
constexpr int H = 4096;
constexpr int I = 11008;
constexpr int GH = 32;   // H/128
constexpr int GI = 86;   // I/128

// async global->LDS, 16B per lane. LDS dest = wave-uniform base + lane*16.
__device__ __forceinline__ void gll16(const void* g, void* l) {
    __builtin_amdgcn_global_load_lds(
        (const __attribute__((address_space(1))) unsigned int*)g,
        (__attribute__((address_space(3))) unsigned int*)l, 16, 0, 0);
}

// dequant 8 int32 (two int4 halves) -> 8 f16:  w = q*s - zp*s
__device__ __forceinline__ f16x8 dq8v(int4 a, int4 b, float sv, float zv) {
    f16x8 r;
    auto p0 = __builtin_amdgcn_cvt_pkrtz((float)a.x * sv - zv, (float)a.y * sv - zv);
    auto p1 = __builtin_amdgcn_cvt_pkrtz((float)a.z * sv - zv, (float)a.w * sv - zv);
    auto p2 = __builtin_amdgcn_cvt_pkrtz((float)b.x * sv - zv, (float)b.y * sv - zv);
    auto p3 = __builtin_amdgcn_cvt_pkrtz((float)b.z * sv - zv, (float)b.w * sv - zv);
    r[0] = p0[0]; r[1] = p0[1]; r[2] = p1[0]; r[3] = p1[1];
    r[4] = p2[0]; r[5] = p2[1]; r[6] = p3[0]; r[7] = p3[1];
    return r;
}

// x [64][4096] f32 -> tiled f16 xp[w:128][m:64][hi:4][8]
__global__ __launch_bounds__(256) void k_cvt(const float* __restrict__ x,
                                             f16* __restrict__ xp) {
    int C = blockIdx.x * 256 + threadIdx.x;        // 0..32767
    int w = C >> 8, m = (C >> 2) & 63, hi = C & 3;
    const float* src = x + (size_t)m * H + w * 32 + hi * 8;
    float4 a = *(const float4*)src;
    float4 b = *(const float4*)(src + 4);
    f16x8 o;
    o[0] = (f16)a.x; o[1] = (f16)a.y; o[2] = (f16)a.z; o[3] = (f16)a.w;
    o[4] = (f16)b.x; o[5] = (f16)b.y; o[6] = (f16)b.z; o[7] = (f16)b.w;
    *(f16x8*)(xp + (size_t)C * 8) = o;
}

// ---------- gate/up partial GEMM, 4-KB-contiguous staging ----------
// grid (688, 4, 2): x = 16-row N-tile, y = K-chunk (1024 ints), z = matrix.
// 256 thr = 4 waves; waves split K (2 groups each); LDS-reduce; write part[by*2+mat].
__global__ __launch_bounds__(256, 2) void k_gateup(
    const f16* __restrict__ xp,
    const int* __restrict__ q1, const float* __restrict__ s1, const int* __restrict__ zp1,
    const int* __restrict__ q3, const float* __restrict__ s3, const int* __restrict__ zp3,
    float* __restrict__ part)
{
    __shared__ int tile[16384];                    // 16 rows x 4KB = 64KB
    __shared__ float xs[4][64][16];                // 16KB wave-reduce buffer
    const int t = threadIdx.x;
    const int wv = t >> 6, lane = t & 63, lo = lane & 15, hi = lane >> 4;
    const int R0 = blockIdx.x * 16;
    const int by = blockIdx.y;                     // K chunk (8 groups)
    const int mat = blockIdx.z;

    const int*   q  = mat ? q3 : q1;
    const float* sm = mat ? s3 : s1;
    const int*   zm = mat ? zp3 : zp1;

    // stage: pass p = row p, 256 threads x 16B = the row's 4KB chunk (contiguous,
    // granule-swizzled per 512B sub-chunk: src granule = (t&31)^(p&7))
    #pragma unroll
    for (int p = 0; p < 16; ++p) {
        size_t gb = (size_t)(R0 + p) * 16384 + (size_t)by * 4096
                  + ((t >> 5) * 512) + (((t & 31) ^ (p & 7)) * 16);
        gll16((const char*)q + gb, (void*)(tile + p * 1024 + wv * 256));
    }
    asm volatile("s_waitcnt vmcnt(0)" ::: "memory");
    __syncthreads();

    const int grow = R0 + lo;                      // this lane's weight row
    f32x4 acc[4] = {};

    #pragma unroll
    for (int s = 0; s < 8; ++s) {
        int kk = wv * 8 + s;                       // 32-int k-step within chunk
        int gg = by * 8 + (kk >> 2);
        float sv = sm[(size_t)grow * GH + gg];
        float zv = (float)zm[(size_t)grow * GH + gg] * sv;

        int gG = kk * 8 + hi * 2;                  // 16B granule within row
        int gl = (gG & ~31) | ((gG & 31) ^ (lo & 7));
        int byte0 = lo * 4096 + gl * 16;
        const char* tb = (const char*)tile;
        int4 b0 = *(const int4*)(tb + byte0);
        int4 b1 = *(const int4*)(tb + (byte0 ^ 16));
        f16x8 bf = dq8v(b0, b1, sv, zv);

        int kkg = by * 32 + kk;                    // global 32-int k-step
        #pragma unroll
        for (int mt = 0; mt < 4; ++mt) {
            f16x8 af = *(const f16x8*)(xp +
                ((size_t)kkg * 256 + (mt * 16 + lo) * 4 + hi) * 8);
            acc[mt] = __builtin_amdgcn_mfma_f32_16x16x32_f16(af, bf, acc[mt], 0, 0, 0);
        }
    }

    #pragma unroll
    for (int mt = 0; mt < 4; ++mt)
        #pragma unroll
        for (int j = 0; j < 4; ++j)
            xs[wv][mt * 16 + hi * 4 + j][lo] = acc[mt][j];
    __syncthreads();

    float* pb = part + (size_t)(by * 2 + mat) * T * I;
    #pragma unroll
    for (int i = 0; i < 4; ++i) {
        int idx = t + i * 256;                     // 0..1023
        int m = idx >> 4, c = idx & 15;
        float v = xs[0][m][c] + xs[1][m][c] + xs[2][m][c] + xs[3][m][c];
        pb[(size_t)m * I + R0 + c] = v;
    }
}

// ---------- combine: h = silu(gate)*up, tiled hp[w:344][m:64][hi:4][8] f16 ----------
__global__ __launch_bounds__(256) void k_comb(const float* __restrict__ part,
                                              f16* __restrict__ hp) {
    int C = blockIdx.x * 256 + threadIdx.x;        // 0..88063
    int w = C >> 8, m = (C >> 2) & 63, hi = C & 3;
    int col = w * 32 + hi * 8;
    float ga[8] = {}, ua[8] = {};
    #pragma unroll
    for (int ks = 0; ks < 4; ++ks) {
        const float* pg = part + ((size_t)(ks * 2 + 0) * T + m) * I + col;
        const float* pu = part + ((size_t)(ks * 2 + 1) * T + m) * I + col;
        float4 g0 = *(const float4*)pg, g1 = *(const float4*)(pg + 4);
        float4 u0 = *(const float4*)pu, u1 = *(const float4*)(pu + 4);
        ga[0] += g0.x; ga[1] += g0.y; ga[2] += g0.z; ga[3] += g0.w;
        ga[4] += g1.x; ga[5] += g1.y; ga[6] += g1.z; ga[7] += g1.w;
        ua[0] += u0.x; ua[1] += u0.y; ua[2] += u0.z; ua[3] += u0.w;
        ua[4] += u1.x; ua[5] += u1.y; ua[6] += u1.z; ua[7] += u1.w;
    }
    f16x8 o;
    #pragma unroll
    for (int j = 0; j < 8; ++j) {
        float gv = ga[j];
        o[j] = (f16)(gv / (1.f + __expf(-gv)) * ua[j]);
    }
    *(f16x8*)(hp + (size_t)C * 8) = o;
}

// ---------- down partial GEMM, 4-KB-contiguous staging ----------
// grid (256, 11): x = 16-row N-tile (H rows), y = K-chunk (8 groups; last 6).
__global__ __launch_bounds__(256, 2) void k_down(
    const f16* __restrict__ hp,
    const int* __restrict__ q2, const float* __restrict__ s2, const int* __restrict__ zp2,
    float* __restrict__ part2)
{
    __shared__ int tile[16384];                    // up to 16 rows x 4KB
    __shared__ float xs[4][64][16];
    const int t = threadIdx.x;
    const int wv = t >> 6, lane = t & 63, lo = lane & 15, hi = lane >> 4;
    const int R0 = blockIdx.x * 16;
    const int by = blockIdx.y;                     // 0..10
    const int CNT = (by < 10) ? 8 : 6;             // groups in this chunk
    const int rowpitch = CNT * 128;                // ints per row in tile

    // stage: pass p = row p; CNT*32 granules per row
    if (wv < (CNT >> 1)) {
        #pragma unroll
        for (int p = 0; p < 16; ++p) {
            size_t gb = (size_t)(R0 + p) * 44032 + (size_t)by * 4096
                      + ((t >> 5) * 512) + (((t & 31) ^ (p & 7)) * 16);
            gll16((const char*)q2 + gb, (void*)(tile + p * rowpitch + wv * 256));
        }
    }
    asm volatile("s_waitcnt vmcnt(0)" ::: "memory");
    __syncthreads();

    const int grow = R0 + lo;
    f32x4 acc[4] = {};

    for (int s = 0; s < CNT; ++s) {
        int kk = wv * CNT + s;                     // 32-int k-step within chunk
        int gg = by * 8 + (kk >> 2);
        float sv = s2[(size_t)grow * GI + gg];
        float zv = (float)zp2[(size_t)grow * GI + gg] * sv;

        int gG = kk * 8 + hi * 2;
        int gl = (gG & ~31) | ((gG & 31) ^ (lo & 7));
        int byte0 = lo * (CNT * 512) + gl * 16;
        const char* tb = (const char*)tile;
        int4 b0 = *(const int4*)(tb + byte0);
        int4 b1 = *(const int4*)(tb + (byte0 ^ 16));
        f16x8 bf = dq8v(b0, b1, sv, zv);

        int kkg = by * 32 + kk;
        #pragma unroll
        for (int mt = 0; mt < 4; ++mt) {
            f16x8 af = *(const f16x8*)(hp +
                ((size_t)kkg * 256 + (mt * 16 + lo) * 4 + hi) * 8);
            acc[mt] = __builtin_amdgcn_mfma_f32_16x16x32_f16(af, bf, acc[mt], 0, 0, 0);
        }
    }

    #pragma unroll
    for (int mt = 0; mt < 4; ++mt)
        #pragma unroll
        for (int j = 0; j < 4; ++j)
            xs[wv][mt * 16 + hi * 4 + j][lo] = acc[mt][j];
    __syncthreads();

    float* pb = part2 + (size_t)by * T * H;
    #pragma unroll
    for (int i = 0; i < 4; ++i) {
        int idx = t + i * 256;
        int m = idx >> 4, c = idx & 15;
        float v = xs[0][m][c] + xs[1][m][c] + xs[2][m][c] + xs[3][m][c];
        pb[(size_t)m * H + R0 + c] = v;
    }
}

// ---------- reduce 11 down-partials -> out f32 ----------
__global__ __launch_bounds__(256) void k_red(const float* __restrict__ part2,
                                             float* __restrict__ out) {
    int i = (blockIdx.x * 256 + threadIdx.x) * 4;
    float4 s = {0.f, 0.f, 0.f, 0.f};
    #pragma unroll
    for (int y = 0; y < 11; ++y) {
        float4 v = *(const float4*)(part2 + (size_t)y * T * H + i);
        s.x += v.x; s.y += v.y; s.z += v.z; s.w += v.w;
    }
    *(float4*)(out + i) = s;
}

extern "C" void kernel_launch(void* const* d_in, const int* in_sizes, int n_in,
                              void* d_out, int out_size, void* d_ws, size_t ws_size,
                              hipStream_t stream) {
    const float* x   = (const float*)d_in[0];
    const int*   q1  = (const int*)d_in[1];
    const float* s1  = (const float*)d_in[2];
    const int*   zp1 = (const int*)d_in[3];
    const int*   q3  = (const int*)d_in[4];
    const float* s3  = (const float*)d_in[5];
    const int*   zp3 = (const int*)d_in[6];
    const int*   q2  = (const int*)d_in[7];
    const float* s2  = (const float*)d_in[8];
    const int*   zp2 = (const int*)d_in[9];

    char* ws = (char*)d_ws;
    f16*   xp    = (f16*)ws;                               // 524,288 B
    f16*   hp    = (f16*)(ws + 524288);                    // 1,409,024 B
    float* part  = (float*)(ws + 1933312);                 // 22,544,384 B
    float* part2 = (float*)(ws + 24477696);                // 11,534,336 B

    k_cvt<<<128, 256, 0, stream>>>(x, xp);
    k_gateup<<<dim3(688, 4, 2), 256, 0, stream>>>(xp, q1, s1, zp1, q3, s3, zp3, part);
    k_comb<<<344, 256, 0, stream>>>(part, hp);
    k_down<<<dim3(256, 11), 256, 0, stream>>>(hp, q2, s2, zp2, part2);
    k_red<<<256, 256, 0, stream>>>(part2, (float*)d_out);
}

// Round 9
// 168.308 us; speedup vs baseline: 1.2865x; 1.2865x over previous
//
#include <hip/hip_runtime.h>
#include <hip/hip_fp16.h>

typedef _Float16 f16;
typedef f16 f16x8 __attribute__((ext_vector_type(8)));
typedef float f32x4 __attribute__((ext_vector_type(4)));

constexpr int T = 64;
constexpr int H = 4096;
constexpr int I = 11008;
constexpr int GH = 32;   // H/128
constexpr int GI = 86;   // I/128

// async global->LDS, 16B per lane. LDS dest is wave-uniform base + lane*16.
__device__ __forceinline__ void gll16(const void* g, void* l) {
    __builtin_amdgcn_global_load_lds(
        (const __attribute__((address_space(1))) unsigned int*)g,
        (__attribute__((address_space(3))) unsigned int*)l, 16, 0, 0);
}

// dequant 8 int32 (two int4 halves) -> 8 f16:  w = q*s - zp*s
__device__ __forceinline__ f16x8 dq8v(int4 a, int4 b, float sv, float zv) {
    f16x8 r;
    auto p0 = __builtin_amdgcn_cvt_pkrtz((float)a.x * sv - zv, (float)a.y * sv - zv);
    auto p1 = __builtin_amdgcn_cvt_pkrtz((float)a.z * sv - zv, (float)a.w * sv - zv);
    auto p2 = __builtin_amdgcn_cvt_pkrtz((float)b.x * sv - zv, (float)b.y * sv - zv);
    auto p3 = __builtin_amdgcn_cvt_pkrtz((float)b.z * sv - zv, (float)b.w * sv - zv);
    r[0] = p0[0]; r[1] = p0[1]; r[2] = p1[0]; r[3] = p1[1];
    r[4] = p2[0]; r[5] = p2[1]; r[6] = p3[0]; r[7] = p3[1];
    return r;
}

// x [64][4096] f32 -> tiled f16 xp[w:128][m:64][hi:4][8]
__global__ __launch_bounds__(256) void k_cvt(const float* __restrict__ x,
                                             f16* __restrict__ xp) {
    int C = blockIdx.x * 256 + threadIdx.x;        // 0..32767
    int w = C >> 8, m = (C >> 2) & 63, hi = C & 3;
    const float* src = x + (size_t)m * H + w * 32 + hi * 8;
    float4 a = *(const float4*)src;
    float4 b = *(const float4*)(src + 4);
    f16x8 o;
    o[0] = (f16)a.x; o[1] = (f16)a.y; o[2] = (f16)a.z; o[3] = (f16)a.w;
    o[4] = (f16)b.x; o[5] = (f16)b.y; o[6] = (f16)b.z; o[7] = (f16)b.w;
    *(f16x8*)(xp + (size_t)C * 8) = o;
}

// stage 64 rows x 128 int32 of one group into LDS buf (32KB), src XOR-pre-swizzled
template<int KDIM>
__device__ __forceinline__ void stage_tile(const int* __restrict__ q, int R0, int g,
                                           int* buf) {
    const int t = threadIdx.x;
    #pragma unroll
    for (int k4 = 0; k4 < 8; ++k4) {
        int P = t + k4 * 256;                      // granule 0..2047
        int row = P >> 5, c = P & 31, cs = c ^ (row & 7);
        size_t gb = (size_t)(R0 + row) * ((size_t)KDIM * 4) + (size_t)g * 512 + cs * 16;
        gll16((const char*)q + gb, (void*)&buf[((t >> 6) * 64 + k4 * 256) * 4]);
    }
}

// ---------- gate/up partial GEMM: part[ks*2+mat][T][I] ----------
// grid (172, 4, 2): x=N-tile, y=K-quarter, z=matrix. 256 thr = 4 waves (nsub).
// Raw s_barrier + counted vmcnt(8): next-tile gll loads stay in flight.
__global__ __launch_bounds__(256, 2) void k_gateup(
    const f16* __restrict__ xp,
    const int* __restrict__ q1, const float* __restrict__ s1, const int* __restrict__ zp1,
    const int* __restrict__ q3, const float* __restrict__ s3, const int* __restrict__ zp3,
    float* __restrict__ part)
{
    __shared__ int tile[2][8192];                  // 2 x 32KB
    const int t = threadIdx.x;
    const int wv = t >> 6, lane = t & 63, lo = lane & 15, hi = lane >> 4;
    const int R0 = blockIdx.x * 64;
    const int ks = blockIdx.y;
    const int mat = blockIdx.z;
    const int brow = wv * 16 + lo;
    const int grow = R0 + brow;

    const int*   q  = mat ? q3 : q1;
    const float* sm = mat ? s3 : s1;
    const int*   zm = mat ? zp3 : zp1;

    f32x4 acc[4] = {};

    stage_tile<H>(q, R0, ks * 8, tile[0]);

    for (int gl = 0; gl < 8; ++gl) {
        int g = ks * 8 + gl;
        float sv = sm[(size_t)grow * GH + g];
        float zv = (float)zm[(size_t)grow * GH + g] * sv;

        f16x8 areg[16];
        #pragma unroll
        for (int w = 0; w < 4; ++w)
            #pragma unroll
            for (int mt = 0; mt < 4; ++mt)
                areg[w * 4 + mt] = *(const f16x8*)(xp +
                    ((size_t)(g * 4 + w) * 256 + (mt * 16 + lo) * 4 + hi) * 8);
        asm volatile("" ::: "memory");

        if (gl < 7) {
            stage_tile<H>(q, R0, g + 1, tile[(gl & 1) ^ 1]);
            asm volatile("s_waitcnt vmcnt(8)" ::: "memory");  // cur tile + areg done; next in flight
        } else {
            asm volatile("s_waitcnt vmcnt(0)" ::: "memory");
        }
        __builtin_amdgcn_s_barrier();              // raw: does NOT drain vmcnt

        const char* tb = (const char*)tile[gl & 1];
        #pragma unroll
        for (int w = 0; w < 4; ++w) {
            int cc = (w * 8 + hi * 2) ^ (brow & 7);
            int byte0 = (brow * 32 + cc) * 16;
            int4 b0 = *(const int4*)(tb + byte0);
            int4 b1 = *(const int4*)(tb + (byte0 ^ 16));
            f16x8 bf = dq8v(b0, b1, sv, zv);
            #pragma unroll
            for (int mt = 0; mt < 4; ++mt)
                acc[mt] = __builtin_amdgcn_mfma_f32_16x16x32_f16(areg[w * 4 + mt], bf, acc[mt], 0, 0, 0);
        }
        __builtin_amdgcn_s_barrier();              // all waves done reading before overwrite
    }

    float* pb = part + (size_t)(ks * 2 + mat) * T * I;
    #pragma unroll
    for (int mt = 0; mt < 4; ++mt)
        #pragma unroll
        for (int j = 0; j < 4; ++j)
            pb[(size_t)(mt * 16 + hi * 4 + j) * I + R0 + brow] = acc[mt][j];
}

// ---------- combine: h = silu(gate)*up, tiled hp[w:344][m:64][hi:4][8] f16 ----------
__global__ __launch_bounds__(256) void k_comb(const float* __restrict__ part,
                                              f16* __restrict__ hp) {
    int C = blockIdx.x * 256 + threadIdx.x;        // 0..88063
    int w = C >> 8, m = (C >> 2) & 63, hi = C & 3;
    int col = w * 32 + hi * 8;
    float ga[8] = {}, ua[8] = {};
    #pragma unroll
    for (int ks = 0; ks < 4; ++ks) {
        const float* pg = part + ((size_t)(ks * 2 + 0) * T + m) * I + col;
        const float* pu = part + ((size_t)(ks * 2 + 1) * T + m) * I + col;
        float4 g0 = *(const float4*)pg, g1 = *(const float4*)(pg + 4);
        float4 u0 = *(const float4*)pu, u1 = *(const float4*)(pu + 4);
        ga[0] += g0.x; ga[1] += g0.y; ga[2] += g0.z; ga[3] += g0.w;
        ga[4] += g1.x; ga[5] += g1.y; ga[6] += g1.z; ga[7] += g1.w;
        ua[0] += u0.x; ua[1] += u0.y; ua[2] += u0.z; ua[3] += u0.w;
        ua[4] += u1.x; ua[5] += u1.y; ua[6] += u1.z; ua[7] += u1.w;
    }
    f16x8 o;
    #pragma unroll
    for (int j = 0; j < 8; ++j) {
        float gv = ga[j];
        o[j] = (f16)(gv / (1.f + __expf(-gv)) * ua[j]);
    }
    *(f16x8*)(hp + (size_t)C * 8) = o;
}

// ---------- down partial GEMM: part2[y][T][H], grid (64, 8), 256 thr ----------
__global__ __launch_bounds__(256, 2) void k_down(
    const f16* __restrict__ hp,
    const int* __restrict__ q2, const float* __restrict__ s2, const int* __restrict__ zp2,
    float* __restrict__ part2)
{
    __shared__ int tile[2][8192];
    const int t = threadIdx.x;
    const int wv = t >> 6, lane = t & 63, lo = lane & 15, hi = lane >> 4;
    const int R0 = blockIdx.x * 64;
    const int y = blockIdx.y;
    const int g0 = (y * GI) >> 3, g1 = ((y + 1) * GI) >> 3;
    const int brow = wv * 16 + lo;
    const int grow = R0 + brow;

    f32x4 acc[4] = {};

    stage_tile<I>(q2, R0, g0, tile[0]);

    int bi = 0;
    for (int g = g0; g < g1; ++g, ++bi) {
        float sv = s2[(size_t)grow * GI + g];
        float zv = (float)zp2[(size_t)grow * GI + g] * sv;

        f16x8 areg[16];
        #pragma unroll
        for (int w = 0; w < 4; ++w)
            #pragma unroll
            for (int mt = 0; mt < 4; ++mt)
                areg[w * 4 + mt] = *(const f16x8*)(hp +
                    ((size_t)(g * 4 + w) * 256 + (mt * 16 + lo) * 4 + hi) * 8);
        asm volatile("" ::: "memory");

        if (g + 1 < g1) {
            stage_tile<I>(q2, R0, g + 1, tile[(bi & 1) ^ 1]);
            asm volatile("s_waitcnt vmcnt(8)" ::: "memory");
        } else {
            asm volatile("s_waitcnt vmcnt(0)" ::: "memory");
        }
        __builtin_amdgcn_s_barrier();

        const char* tb = (const char*)tile[bi & 1];
        #pragma unroll
        for (int w = 0; w < 4; ++w) {
            int cc = (w * 8 + hi * 2) ^ (brow & 7);
            int byte0 = (brow * 32 + cc) * 16;
            int4 b0 = *(const int4*)(tb + byte0);
            int4 b1 = *(const int4*)(tb + (byte0 ^ 16));
            f16x8 bf = dq8v(b0, b1, sv, zv);
            #pragma unroll
            for (int mt = 0; mt < 4; ++mt)
                acc[mt] = __builtin_amdgcn_mfma_f32_16x16x32_f16(areg[w * 4 + mt], bf, acc[mt], 0, 0, 0);
        }
        __builtin_amdgcn_s_barrier();
    }

    float* pb = part2 + (size_t)y * T * H;
    #pragma unroll
    for (int mt = 0; mt < 4; ++mt)
        #pragma unroll
        for (int j = 0; j < 4; ++j)
            pb[(size_t)(mt * 16 + hi * 4 + j) * H + R0 + brow] = acc[mt][j];
}

// ---------- reduce 8 down-partials -> out f32 ----------
__global__ __launch_bounds__(256) void k_red(const float* __restrict__ part2,
                                             float* __restrict__ out) {
    int i = (blockIdx.x * 256 + threadIdx.x) * 4;
    float4 s = {0.f, 0.f, 0.f, 0.f};
    #pragma unroll
    for (int y = 0; y < 8; ++y) {
        float4 v = *(const float4*)(part2 + (size_t)y * T * H + i);
        s.x += v.x; s.y += v.y; s.z += v.z; s.w += v.w;
    }
    *(float4*)(out + i) = s;
}

extern "C" void kernel_launch(void* const* d_in, const int* in_sizes, int n_in,
                              void* d_out, int out_size, void* d_ws, size_t ws_size,
                              hipStream_t stream) {
    const float* x   = (const float*)d_in[0];
    const int*   q1  = (const int*)d_in[1];
    const float* s1  = (const float*)d_in[2];
    const int*   zp1 = (const int*)d_in[3];
    const int*   q3  = (const int*)d_in[4];
    const float* s3  = (const float*)d_in[5];
    const int*   zp3 = (const int*)d_in[6];
    const int*   q2  = (const int*)d_in[7];
    const float* s2  = (const float*)d_in[8];
    const int*   zp2 = (const int*)d_in[9];

    char* ws = (char*)d_ws;
    f16*   xp    = (f16*)ws;                               // 524,288 B
    f16*   hp    = (f16*)(ws + 524288);                    // 1,409,024 B
    float* part  = (float*)(ws + 1933312);                 // 22,544,384 B
    float* part2 = (float*)(ws + 24477696);                // 8,388,608 B

    k_cvt<<<128, 256, 0, stream>>>(x, xp);
    k_gateup<<<dim3(172, 4, 2), 256, 0, stream>>>(xp, q1, s1, zp1, q3, s3, zp3, part);
    k_comb<<<344, 256, 0, stream>>>(part, hp);
    k_down<<<dim3(64, 8), 256, 0, stream>>>(hp, q2, s2, zp2, part2);
    k_red<<<256, 256, 0, stream>>>(part2, (float*)d_out);
}